// Round 14
// baseline (155.054 us; speedup 1.0000x reference)
//
#include <hip/hip_runtime.h>
#include <stdint.h>

#define B_ 2048
#define T_ 256
#define V_ 128
#define E_ 128
#define H_ 64
#define G4_ 256  // 4*H
#define POS_W 20.0f
#define MB_ 4            // batch rows per block: row j at M-row 4j (C-reg[0] of lane quad j)
#define NBLK_ (B_ / MB_) // 512 blocks = 2 blocks/CU = 2 waves/SIMD (proven best shape)
typedef _Float16 half1;
typedef __attribute__((ext_vector_type(8))) _Float16 f16x8;
typedef __attribute__((ext_vector_type(4))) float f32x4;

#if __has_builtin(__builtin_amdgcn_exp2f)
#define EXP2F(x) __builtin_amdgcn_exp2f(x)
#else
#define EXP2F(x) exp2f(x)
#endif

#if __has_builtin(__builtin_amdgcn_rcpf)
#define RCPF(x) __builtin_amdgcn_rcpf(x)
#else
#define RCPF(x) (1.0f / (x))
#endif

#define L2E 1.44269504f

// Barrier draining ONLY lgkmcnt: keeps L2 proj-prefetches (vmcnt) in flight
// across the step boundary. Safe: h-exchange is double-buffered; in-flight
// global loads only write registers.
__device__ __forceinline__ void lds_barrier() {
    asm volatile("s_waitcnt lgkmcnt(0)\n\ts_barrier" ::: "memory");
}

// Merged-rcp cell (R8-verified): gate args arrive PRE-SCALED (bf and projC
// carry s_g = -L2E for i,f,o and +2*L2E for g). 5 exp2 + 2 rcp.
__device__ __forceinline__ void cell_update(float g0, float g1, float g2, float g3,
                                            float& cA, float& hA) {
    float ei = EXP2F(g0);
    float ef = EXP2F(g1);
    float eg = EXP2F(g2);
    float eo = EXP2F(g3);
    float onei = 1.0f + ei;
    float oneg = eg + 1.0f;
    float onef = 1.0f + ef;
    float P = onei * oneg;
    float D1 = P * onef;
    float N1 = __builtin_fmaf(cA, P, (eg - 1.0f) * onef);
    cA = N1 * RCPF(D1);
    float ct = fminf(fmaxf(cA, -15.0f), 15.0f);
    float et = EXP2F(2.0f * L2E * ct);
    float D2 = (1.0f + eo) * (et + 1.0f);
    hA = (et - 1.0f) * RCPF(D2);
}

// ---------------------------------------------------------------------------
// k_prep: projC[v][u][g] = s_g * (dot(emb[v], W_ih[g*64+u]) + b_ih + b_hh)
// s_g = -L2E for gates i,f,o; +2*L2E for gate g (scale-fold, R9/R10-verified).
// ---------------------------------------------------------------------------
__global__ void k_prep(const float* __restrict__ emb, const float* __restrict__ Wih,
                       const float* __restrict__ bih, const float* __restrict__ bhh,
                       float* __restrict__ projC, float* __restrict__ loss_slot) {
    int tid = threadIdx.x;  // 0..255; u = tid>>2, g = tid&3
    int v = blockIdx.x;
    if (v == 0 && tid == 0) *loss_slot = 0.0f;
    int u = tid >> 2, g = tid & 3;
    int row = g * 64 + u;
    const float4* e4 = (const float4*)(emb + v * E_);
    const float4* w4 = (const float4*)(Wih + row * E_);
    float acc = bih[row] + bhh[row];
#pragma unroll
    for (int i = 0; i < E_ / 4; ++i) {
        float4 a = e4[i];
        float4 b = w4[i];
        acc += a.x * b.x + a.y * b.y + a.z * b.z + a.w * b.w;
    }
    float s = (g == 2) ? (2.0f * L2E) : (-L2E);
    projC[v * G4_ + tid] = acc * s;  // coalesced
}

// ---------------------------------------------------------------------------
// k_lstm R14 = R11 (confirmed optimum, 86.4us) + s_setprio chain bias.
// T5 regime check: setprio is null in lockstep structures but +4-7% where
// independent blocks sit at different phases — here each SIMD hosts 2 waves
// from two INDEPENDENT blocks (unsynchronized barriers). prio=1 over the
// serial chain {ds_read -> MFMA -> cell -> publish}, prio=0 while waiting:
// the co-resident wave's MFMA/prefetch issue fills the chain wave's trans
// latency holes instead of competing for issue slots.
// Ledger: T=811 = MFMA 258 + VALU-only 138 + ~415 exposed chain latency;
// target is converting stall into overlap. All structural alternatives
// measured worse (R5/R6/R7/R9/R10); issue cuts exhausted (R12).
// ---------------------------------------------------------------------------
__launch_bounds__(256, 2)
__global__ void k_lstm(const int* __restrict__ x, const float* __restrict__ Whh,
                       const float* __restrict__ projC, const float* __restrict__ Wfc,
                       const float* __restrict__ bfc, const float* __restrict__ targets,
                       float* __restrict__ logits, float* __restrict__ loss_slot) {
    int b0 = blockIdx.x * MB_;
    int t = threadIdx.x;         // 0..255
    int w = t >> 6, l = t & 63;  // wave, lane
    int q = l >> 4, cc = l & 15;
    int u = 16 * w + cc;  // unit owned by this lane (all 4 gates), batch row q

    __shared__ __align__(16) half1 hf[2][1024];  // A-layout h, double-buffered
    __shared__ int xT[T_][MB_];                  // token byte-offsets (tok<<10)
    __shared__ float hfin[MB_][68];              // final h (padded)
    __shared__ float zred[MB_];

    // stage xT (coalesced: fixed i, consecutive t); pre-scale to byte offset
#pragma unroll
    for (int i = 0; i < MB_; ++i) xT[t][i] = x[(b0 + i) * T_ + t] << 10;  // *G4_*4
    ((float*)hf)[t] = 0.0f;
    ((float*)hf)[t + 256] = 0.0f;
    ((float*)hf)[t + 512] = 0.0f;
    ((float*)hf)[t + 768] = 0.0f;
    __syncthreads();

    // B-fragments from W_hh (f32, L2), gate scale s_jj FOLDED IN.
    // frag elem j: B[k=c*32+q*8+j][col cc] = s_jj * Whh[jj*64+16w+cc][k]
    f16x8 bf[4][2];
#pragma unroll
    for (int jj = 0; jj < 4; ++jj) {
        float s = (jj == 2) ? (2.0f * L2E) : (-L2E);
#pragma unroll
        for (int c = 0; c < 2; ++c) {
            int row = jj * 64 + 16 * w + cc;
            int kb = c * 32 + q * 8;
            float4 w0 = *(const float4*)(Whh + row * H_ + kb);
            float4 w1 = *(const float4*)(Whh + row * H_ + kb + 4);
            f16x8 tmp;
            tmp[0] = (half1)(w0.x * s); tmp[1] = (half1)(w0.y * s);
            tmp[2] = (half1)(w0.z * s); tmp[3] = (half1)(w0.w * s);
            tmp[4] = (half1)(w1.x * s); tmp[5] = (half1)(w1.y * s);
            tmp[6] = (half1)(w1.z * s); tmp[7] = (half1)(w1.w * s);
            bf[jj][c] = tmp;
        }
    }

    // h-write slot for (unit u, M-row 4q):
    // f16 idx = (u>>5)*512 + ((u>>3)&3)*128 + (4q)*8 + (u&7)
    int hbase = (u >> 5) * 512 + ((u >> 3) & 3) * 128 + (4 * q) * 8 + (u & 7);

    float cA = 0.0f, hA = 0.0f;
    const char* pcu = (const char*)projC + (u << 4);  // projC + u*16 bytes (hoisted)

    // depth-1 proj pipeline: pp for step 0; token byte-offset for step 1
    f32x4 ppA = *(const f32x4*)(pcu + xT[0][q]);
    int xcA = xT[1][q];

    const f32x4 z4 = {0.0f, 0.0f, 0.0f, 0.0f};
    int p = 0;
#pragma unroll 2
    for (int step = 0; step < T_; ++step) {
        __builtin_amdgcn_s_setprio(1);  // chain start: bias issue to this wave
        // ---- chain head: A-fragments of h_t (conflict-free lane-contiguous b128)
        const f16x8 a0 = *(const f16x8*)(hf[p] + l * 8);
        const f16x8 a1 = *(const f16x8*)(hf[p] + 512 + l * 8);

        // 8 MFMAs, unchained pairs, constant z4 C (no per-MFMA C movs).
        f32x4 d0[4], d1[4];
#pragma unroll
        for (int jj = 0; jj < 4; ++jj) {
            d0[jj] = __builtin_amdgcn_mfma_f32_16x16x32_f16(a0, bf[jj][0], z4, 0, 0, 0);
            d1[jj] = __builtin_amdgcn_mfma_f32_16x16x32_f16(a1, bf[jj][1], z4, 0, 0, 0);
        }

        // ---- off-chain (MFMA shadow): proj for step+1, token for step+2
        f32x4 pnA = *(const f32x4*)(pcu + xcA);
        int xnA = xT[(step + 2) & (T_ - 1)][q];

        // ---- chain tail: gates (pre-scaled) = d0 + d1 + pp, then merged cell
        float g0 = d0[0][0] + d1[0][0] + ppA[0];
        float g1 = d0[1][0] + d1[1][0] + ppA[1];
        float g2 = d0[2][0] + d1[2][0] + ppA[2];
        float g3 = d0[3][0] + d1[3][0] + ppA[3];
        cell_update(g0, g1, g2, g3, cA, hA);

        // publish h_{t+1} (A-layout, other buffer)
        hf[p ^ 1][hbase] = (half1)hA;
        __builtin_amdgcn_s_setprio(0);  // chain done: yield issue to co-resident wave

        ppA = pnA;
        xcA = xnA;
        p ^= 1;
        lds_barrier();  // lgkm-only: the proj prefetch stays in flight
    }

    // epilogue: logits + fused loss
    hfin[q][u] = hA;
    __syncthreads();
    int m4 = t >> 6, uu = t & 63;  // wave m4 reduces batch row m4
    float part = hfin[m4][uu] * Wfc[uu];
#pragma unroll
    for (int off = 32; off > 0; off >>= 1) part += __shfl_down(part, off, 64);
    if (uu == 0) {
        float z = part + bfc[0];
        logits[b0 + m4] = z;
        float tg = targets[b0 + m4];
        float e = EXP2F(-L2E * fabsf(z));
        float lsp = fminf(z, 0.0f) - log1pf(e);
        float lsn = lsp - z;
        zred[m4] = -(POS_W * tg * lsp + (1.0f - tg) * lsn) * (1.0f / (float)B_);
    }
    __syncthreads();
    if (t == 0) {
        float s = 0.0f;
#pragma unroll
        for (int i = 0; i < MB_; ++i) s += zred[i];
        atomicAdd(loss_slot, s);
    }
}

// ---------------------------------------------------------------------------
extern "C" void kernel_launch(void* const* d_in, const int* in_sizes, int n_in,
                              void* d_out, int out_size, void* d_ws, size_t ws_size,
                              hipStream_t stream) {
    const int* x = (const int*)d_in[0];
    const float* targets = (const float*)d_in[1];
    const float* emb = (const float*)d_in[2];
    const float* Wih = (const float*)d_in[3];
    const float* Whh = (const float*)d_in[4];
    const float* bih = (const float*)d_in[5];
    const float* bhh = (const float*)d_in[6];
    const float* Wfc = (const float*)d_in[7];
    const float* bfc = (const float*)d_in[8];
    float* out = (float*)d_out;  // [0..2047] logits, [2048] loss

    float* projC = (float*)d_ws;  // 128*256*4 = 128 KiB

    k_prep<<<dim3(V_), dim3(256), 0, stream>>>(emb, Wih, bih, bhh, projC, out + B_);
    k_lstm<<<dim3(NBLK_), dim3(256), 0, stream>>>(x, Whh, projC, Wfc, bfc, targets, out,
                                                  out + B_);
}

// Round 15
// 150.311 us; speedup vs baseline: 1.0316x; 1.0316x over previous
//
#include <hip/hip_runtime.h>
#include <stdint.h>

#define B_ 2048
#define T_ 256
#define V_ 128
#define E_ 128
#define H_ 64
#define G4_ 256  // 4*H
#define POS_W 20.0f
#define MB_ 4            // batch rows per block: row j at M-row 4j (C-reg[0] of lane quad j)
#define NBLK_ (B_ / MB_) // 512 blocks = 2 blocks/CU = 2 waves/SIMD (proven best shape)
typedef _Float16 half1;
typedef __attribute__((ext_vector_type(8))) _Float16 f16x8;
typedef __attribute__((ext_vector_type(4))) float f32x4;

#if __has_builtin(__builtin_amdgcn_exp2f)
#define EXP2F(x) __builtin_amdgcn_exp2f(x)
#else
#define EXP2F(x) exp2f(x)
#endif

#if __has_builtin(__builtin_amdgcn_rcpf)
#define RCPF(x) __builtin_amdgcn_rcpf(x)
#else
#define RCPF(x) (1.0f / (x))
#endif

#define L2E 1.44269504f

// Barrier draining ONLY lgkmcnt: keeps L2 proj-prefetches (vmcnt) in flight
// across the step boundary. Safe: h-exchange is double-buffered; in-flight
// global loads only write registers.
__device__ __forceinline__ void lds_barrier() {
    asm volatile("s_waitcnt lgkmcnt(0)\n\ts_barrier" ::: "memory");
}

// Merged-rcp cell (R8-verified): gate args arrive PRE-SCALED (bf and projC
// carry s_g = -L2E for i,f,o and +2*L2E for g). 5 exp2 + 2 rcp.
__device__ __forceinline__ void cell_update(float g0, float g1, float g2, float g3,
                                            float& cA, float& hA) {
    float ei = EXP2F(g0);
    float ef = EXP2F(g1);
    float eg = EXP2F(g2);
    float eo = EXP2F(g3);
    float onei = 1.0f + ei;
    float oneg = eg + 1.0f;
    float onef = 1.0f + ef;
    float P = onei * oneg;
    float D1 = P * onef;
    float N1 = __builtin_fmaf(cA, P, (eg - 1.0f) * onef);
    cA = N1 * RCPF(D1);
    float ct = fminf(fmaxf(cA, -15.0f), 15.0f);
    float et = EXP2F(2.0f * L2E * ct);
    float D2 = (1.0f + eo) * (et + 1.0f);
    hA = (et - 1.0f) * RCPF(D2);
}

// ---------------------------------------------------------------------------
// k_prep: projC[v][u][g] = s_g * (dot(emb[v], W_ih[g*64+u]) + b_ih + b_hh)
// s_g = -L2E for gates i,f,o; +2*L2E for gate g (scale-fold, R9/R10-verified).
// ---------------------------------------------------------------------------
__global__ void k_prep(const float* __restrict__ emb, const float* __restrict__ Wih,
                       const float* __restrict__ bih, const float* __restrict__ bhh,
                       float* __restrict__ projC, float* __restrict__ loss_slot) {
    int tid = threadIdx.x;  // 0..255; u = tid>>2, g = tid&3
    int v = blockIdx.x;
    if (v == 0 && tid == 0) *loss_slot = 0.0f;
    int u = tid >> 2, g = tid & 3;
    int row = g * 64 + u;
    const float4* e4 = (const float4*)(emb + v * E_);
    const float4* w4 = (const float4*)(Wih + row * E_);
    float acc = bih[row] + bhh[row];
#pragma unroll
    for (int i = 0; i < E_ / 4; ++i) {
        float4 a = e4[i];
        float4 b = w4[i];
        acc += a.x * b.x + a.y * b.y + a.z * b.z + a.w * b.w;
    }
    float s = (g == 2) ? (2.0f * L2E) : (-L2E);
    projC[v * G4_ + tid] = acc * s;  // coalesced
}

// ---------------------------------------------------------------------------
// k_lstm FINAL = R11/R13, the measured optimum (86.4us kernel, ~150.5us
// total). R14's setprio variant regressed -5% and is reverted (quasi-
// lockstep co-resident blocks: prio starves exactly the overlap that
// fills the chain's latency holes).
// Structure: MB=4, 512 blocks, 2/CU. Verified wins stacked here:
//  - z4 constant C for BOTH MFMAs; pp joins by post-add (no C-mov building)
//  - scale-fold into bf/projC: exp2 args straight off the gate adds
//  - merged-rcp cell (5 exp2 + 2 rcp)
//  - depth-1 proj prefetch + hoisted pcu pointer; register token pipeline
//  - lgkm-only barrier (global prefetches never drained)
// Closed ledger: T=811 cyc/step = MFMA 258 + VALU-only 138 + ~415 exposed
// recurrence-chain latency (~50% stochastic cross-block overlap). This is
// a sequential-dependence latency floor (256 serial steps), not a counter
// roofline. Measured-worse alternatives: R0/R7/R9/R14 (convoy-breaking),
// R1/R5/R6/R10 (decomposition), R12 (micro-cuts past R11).
// ---------------------------------------------------------------------------
__launch_bounds__(256, 2)
__global__ void k_lstm(const int* __restrict__ x, const float* __restrict__ Whh,
                       const float* __restrict__ projC, const float* __restrict__ Wfc,
                       const float* __restrict__ bfc, const float* __restrict__ targets,
                       float* __restrict__ logits, float* __restrict__ loss_slot) {
    int b0 = blockIdx.x * MB_;
    int t = threadIdx.x;         // 0..255
    int w = t >> 6, l = t & 63;  // wave, lane
    int q = l >> 4, cc = l & 15;
    int u = 16 * w + cc;  // unit owned by this lane (all 4 gates), batch row q

    __shared__ __align__(16) half1 hf[2][1024];  // A-layout h, double-buffered
    __shared__ int xT[T_][MB_];                  // token byte-offsets (tok<<10)
    __shared__ float hfin[MB_][68];              // final h (padded)
    __shared__ float zred[MB_];

    // stage xT (coalesced: fixed i, consecutive t); pre-scale to byte offset
#pragma unroll
    for (int i = 0; i < MB_; ++i) xT[t][i] = x[(b0 + i) * T_ + t] << 10;  // *G4_*4
    ((float*)hf)[t] = 0.0f;
    ((float*)hf)[t + 256] = 0.0f;
    ((float*)hf)[t + 512] = 0.0f;
    ((float*)hf)[t + 768] = 0.0f;
    __syncthreads();

    // B-fragments from W_hh (f32, L2), gate scale s_jj FOLDED IN.
    // frag elem j: B[k=c*32+q*8+j][col cc] = s_jj * Whh[jj*64+16w+cc][k]
    f16x8 bf[4][2];
#pragma unroll
    for (int jj = 0; jj < 4; ++jj) {
        float s = (jj == 2) ? (2.0f * L2E) : (-L2E);
#pragma unroll
        for (int c = 0; c < 2; ++c) {
            int row = jj * 64 + 16 * w + cc;
            int kb = c * 32 + q * 8;
            float4 w0 = *(const float4*)(Whh + row * H_ + kb);
            float4 w1 = *(const float4*)(Whh + row * H_ + kb + 4);
            f16x8 tmp;
            tmp[0] = (half1)(w0.x * s); tmp[1] = (half1)(w0.y * s);
            tmp[2] = (half1)(w0.z * s); tmp[3] = (half1)(w0.w * s);
            tmp[4] = (half1)(w1.x * s); tmp[5] = (half1)(w1.y * s);
            tmp[6] = (half1)(w1.z * s); tmp[7] = (half1)(w1.w * s);
            bf[jj][c] = tmp;
        }
    }

    // h-write slot for (unit u, M-row 4q):
    // f16 idx = (u>>5)*512 + ((u>>3)&3)*128 + (4q)*8 + (u&7)
    int hbase = (u >> 5) * 512 + ((u >> 3) & 3) * 128 + (4 * q) * 8 + (u & 7);

    float cA = 0.0f, hA = 0.0f;
    const char* pcu = (const char*)projC + (u << 4);  // projC + u*16 bytes (hoisted)

    // depth-1 proj pipeline: pp for step 0; token byte-offset for step 1
    f32x4 ppA = *(const f32x4*)(pcu + xT[0][q]);
    int xcA = xT[1][q];

    const f32x4 z4 = {0.0f, 0.0f, 0.0f, 0.0f};
    int p = 0;
#pragma unroll 2
    for (int step = 0; step < T_; ++step) {
        // ---- chain head: A-fragments of h_t (conflict-free lane-contiguous b128)
        const f16x8 a0 = *(const f16x8*)(hf[p] + l * 8);
        const f16x8 a1 = *(const f16x8*)(hf[p] + 512 + l * 8);

        // 8 MFMAs, unchained pairs, constant z4 C (no per-MFMA C movs).
        f32x4 d0[4], d1[4];
#pragma unroll
        for (int jj = 0; jj < 4; ++jj) {
            d0[jj] = __builtin_amdgcn_mfma_f32_16x16x32_f16(a0, bf[jj][0], z4, 0, 0, 0);
            d1[jj] = __builtin_amdgcn_mfma_f32_16x16x32_f16(a1, bf[jj][1], z4, 0, 0, 0);
        }

        // ---- off-chain (MFMA shadow): proj for step+1, token for step+2
        f32x4 pnA = *(const f32x4*)(pcu + xcA);
        int xnA = xT[(step + 2) & (T_ - 1)][q];

        // ---- chain tail: gates (pre-scaled) = d0 + d1 + pp, then merged cell
        float g0 = d0[0][0] + d1[0][0] + ppA[0];
        float g1 = d0[1][0] + d1[1][0] + ppA[1];
        float g2 = d0[2][0] + d1[2][0] + ppA[2];
        float g3 = d0[3][0] + d1[3][0] + ppA[3];
        cell_update(g0, g1, g2, g3, cA, hA);

        // publish h_{t+1} (A-layout, other buffer)
        hf[p ^ 1][hbase] = (half1)hA;

        ppA = pnA;
        xcA = xnA;
        p ^= 1;
        lds_barrier();  // lgkm-only: the proj prefetch stays in flight
    }

    // epilogue: logits + fused loss
    hfin[q][u] = hA;
    __syncthreads();
    int m4 = t >> 6, uu = t & 63;  // wave m4 reduces batch row m4
    float part = hfin[m4][uu] * Wfc[uu];
#pragma unroll
    for (int off = 32; off > 0; off >>= 1) part += __shfl_down(part, off, 64);
    if (uu == 0) {
        float z = part + bfc[0];
        logits[b0 + m4] = z;
        float tg = targets[b0 + m4];
        float e = EXP2F(-L2E * fabsf(z));
        float lsp = fminf(z, 0.0f) - log1pf(e);
        float lsn = lsp - z;
        zred[m4] = -(POS_W * tg * lsp + (1.0f - tg) * lsn) * (1.0f / (float)B_);
    }
    __syncthreads();
    if (t == 0) {
        float s = 0.0f;
#pragma unroll
        for (int i = 0; i < MB_; ++i) s += zred[i];
        atomicAdd(loss_slot, s);
    }
}

// ---------------------------------------------------------------------------
extern "C" void kernel_launch(void* const* d_in, const int* in_sizes, int n_in,
                              void* d_out, int out_size, void* d_ws, size_t ws_size,
                              hipStream_t stream) {
    const int* x = (const int*)d_in[0];
    const float* targets = (const float*)d_in[1];
    const float* emb = (const float*)d_in[2];
    const float* Wih = (const float*)d_in[3];
    const float* Whh = (const float*)d_in[4];
    const float* bih = (const float*)d_in[5];
    const float* bhh = (const float*)d_in[6];
    const float* Wfc = (const float*)d_in[7];
    const float* bfc = (const float*)d_in[8];
    float* out = (float*)d_out;  // [0..2047] logits, [2048] loss

    float* projC = (float*)d_ws;  // 128*256*4 = 128 KiB

    k_prep<<<dim3(V_), dim3(256), 0, stream>>>(emb, Wih, bih, bhh, projC, out + B_);
    k_lstm<<<dim3(NBLK_), dim3(256), 0, stream>>>(x, Whh, projC, Wfc, bfc, targets, out,
                                                  out + B_);
}